// Round 4
// baseline (904.494 us; speedup 1.0000x reference)
//
#include <hip/hip_runtime.h>
#include <math.h>

#define NN 100000
#define EE 1600000
#define D 128
#define NCHUNK ((NN + 255) / 256)   // 391

typedef __attribute__((ext_vector_type(8))) short short8;
typedef __attribute__((ext_vector_type(4))) float floatx4;

// ---------- helpers ----------
static __device__ __forceinline__ unsigned short f2bf(float f) {
  unsigned int u = __builtin_bit_cast(unsigned int, f);
  u = (u + 0x7fff + ((u >> 16) & 1)) >> 16;   // RNE
  return (unsigned short)u;
}
static __device__ __forceinline__ unsigned int pk2(float a, float b) {
  return (unsigned int)f2bf(a) | ((unsigned int)f2bf(b) << 16);
}
static __device__ __forceinline__ float bflo(unsigned int u) { return __builtin_bit_cast(float, u << 16); }
static __device__ __forceinline__ float bfhi(unsigned int u) { return __builtin_bit_cast(float, u & 0xffff0000u); }
static __device__ __forceinline__ float bf2f(unsigned short s) {
  return __builtin_bit_cast(float, (unsigned int)s << 16);
}
static __device__ __forceinline__ float sig_f(float x) { return 1.f / (1.f + __expf(-x)); }
static __device__ __forceinline__ float tanh_f(float x) {
  float e = __expf(2.f * x);
  return 1.f - 2.f / (e + 1.f);
}

// ================= CSR binning =================

__global__ __launch_bounds__(256) void k_hist(const int* __restrict__ erow, int* __restrict__ cnt) {
  int e = blockIdx.x * 256 + threadIdx.x;
  if (e < EE) atomicAdd(&cnt[erow[e]], 1);
}

__global__ __launch_bounds__(256) void k_chunk_sum(const int* __restrict__ cnt, int* __restrict__ csum) {
  __shared__ int s[256];
  int i = blockIdx.x * 256 + threadIdx.x;
  s[threadIdx.x] = (i < NN) ? cnt[i] : 0;
  __syncthreads();
  for (int d = 128; d > 0; d >>= 1) {
    if (threadIdx.x < d) s[threadIdx.x] += s[threadIdx.x + d];
    __syncthreads();
  }
  if (threadIdx.x == 0) csum[blockIdx.x] = s[0];
}

__global__ __launch_bounds__(512) void k_chunk_scan(const int* __restrict__ csum, int* __restrict__ coff) {
  __shared__ int s[512];
  int t = threadIdx.x;
  int v = (t < NCHUNK) ? csum[t] : 0;
  s[t] = v;
  __syncthreads();
  for (int d = 1; d < 512; d <<= 1) {
    int tv = (t >= d) ? s[t - d] : 0;
    __syncthreads();
    s[t] += tv;
    __syncthreads();
  }
  if (t < NCHUNK) coff[t] = s[t] - v;  // exclusive
}

__global__ __launch_bounds__(256) void k_row_start(const int* __restrict__ cnt, const int* __restrict__ coff,
                                                   int* __restrict__ row_start, int* __restrict__ cursor) {
  __shared__ int s[256];
  int i = blockIdx.x * 256 + threadIdx.x;
  int v = (i < NN) ? cnt[i] : 0;
  s[threadIdx.x] = v;
  __syncthreads();
  for (int d = 1; d < 256; d <<= 1) {
    int tv = (threadIdx.x >= d) ? s[threadIdx.x - d] : 0;
    __syncthreads();
    s[threadIdx.x] += tv;
    __syncthreads();
  }
  int excl = s[threadIdx.x] - v + coff[blockIdx.x];
  if (i < NN) { row_start[i] = excl; cursor[i] = 0; }
  if (i == NN - 1) row_start[NN] = excl + v;
}

__global__ __launch_bounds__(256) void k_scatter(const int* __restrict__ erow, const int* __restrict__ ecol,
                                                 const float* __restrict__ ew,
                                                 const int* __restrict__ row_start, int* __restrict__ cursor,
                                                 int2* __restrict__ edata) {
  int e = blockIdx.x * 256 + threadIdx.x;
  if (e >= EE) return;
  int r = erow[e];
  int pos = row_start[r] + atomicAdd(&cursor[r], 1);
  int2 out;
  out.x = ecol[e];
  out.y = __builtin_bit_cast(int, ew[e]);
  edata[pos] = out;
}

// ================= weight packing into MFMA B-fragment order =================
// b_frag[lane][j] = W_zr[o = nt*16 + (lane&15)][c = ks*32 + (lane>>4)*8 + j]
__global__ __launch_bounds__(64) void k_pack_zr(const float* __restrict__ ugW, const float* __restrict__ rgW,
                                                unsigned int* __restrict__ packZR) {
  int g = blockIdx.x;           // g = nt*8 + ks, nt 0..15, ks 0..7
  int nt = g >> 3, ks = g & 7;
  int lane = threadIdx.x;
  int o = nt * 16 + (lane & 15);
  int c0 = ks * 32 + (lane >> 4) * 8;
  const float* src = (o < 128 ? ugW + (size_t)o * 256 : rgW + (size_t)(o - 128) * 256) + c0;
  float4 f0 = ((const float4*)src)[0];
  float4 f1 = ((const float4*)src)[1];
  uint4 out;
  out.x = pk2(f0.x, f0.y);
  out.y = pk2(f0.z, f0.w);
  out.z = pk2(f1.x, f1.y);
  out.w = pk2(f1.z, f1.w);
  ((uint4*)packZR)[g * 64 + lane] = out;
}

// b_frag[lane][j] = M[k = ks*32 + (lane>>4)*8 + j][n = nt*16 + (lane&15)]  (M row-major [k][128])
__global__ __launch_bounds__(64) void k_pack_kn(const float* __restrict__ M, unsigned int* __restrict__ pack) {
  int g = blockIdx.x;           // g = nt*4 + ks, nt 0..7, ks 0..3
  int nt = g >> 2, ks = g & 3;
  int lane = threadIdx.x;
  int n = nt * 16 + (lane & 15);
  int k0 = ks * 32 + (lane >> 4) * 8;
  unsigned short v[8];
#pragma unroll
  for (int j = 0; j < 8; ++j) v[j] = f2bf(M[(size_t)(k0 + j) * 128 + n]);
  uint4 out;
  out.x = (unsigned int)v[0] | ((unsigned int)v[1] << 16);
  out.y = (unsigned int)v[2] | ((unsigned int)v[3] << 16);
  out.z = (unsigned int)v[4] | ((unsigned int)v[5] << 16);
  out.w = (unsigned int)v[6] | ((unsigned int)v[7] << 16);
  ((uint4*)pack)[g * 64 + lane] = out;
}

// ================= h0 = X @ W + b via MFMA =================
__global__ __launch_bounds__(256) void init_mfma(
    const float* __restrict__ X, const short* __restrict__ packW, const float* __restrict__ bias,
    float* __restrict__ h, unsigned short* __restrict__ h_bf) {
  __shared__ __align__(16) short sX[32 * 136];   // [row][k], stride 136 bf16
  const int tid = threadIdx.x;
  const int row0 = blockIdx.x * 32;

  {
    int r = tid >> 3, ch = tid & 7;              // 16-float chunk per thread
    const float4* px = (const float4*)(X + (size_t)(row0 + r) * D + ch * 16);
    float4 f0 = px[0], f1 = px[1], f2 = px[2], f3 = px[3];
    uint4 o0, o1;
    o0.x = pk2(f0.x, f0.y); o0.y = pk2(f0.z, f0.w);
    o0.z = pk2(f1.x, f1.y); o0.w = pk2(f1.z, f1.w);
    o1.x = pk2(f2.x, f2.y); o1.y = pk2(f2.z, f2.w);
    o1.z = pk2(f3.x, f3.y); o1.w = pk2(f3.z, f3.w);
    *(uint4*)(sX + r * 136 + ch * 16) = o0;
    *(uint4*)(sX + r * 136 + ch * 16 + 8) = o1;
  }
  __syncthreads();

  const int wave = tid >> 6, lane = tid & 63;
  const int quad = lane >> 4, l15 = lane & 15;
  const int mh = wave & 1, nh = wave >> 1;
  const int mrow = mh * 16 + l15;

  floatx4 acc[4];
  const floatx4 zero4 = {0.f, 0.f, 0.f, 0.f};
#pragma unroll
  for (int t = 0; t < 4; ++t) acc[t] = zero4;

  const short8* pW = (const short8*)packW;
#pragma unroll
  for (int ks = 0; ks < 4; ++ks) {
    short8 a = *(const short8*)(sX + mrow * 136 + ks * 32 + quad * 8);
#pragma unroll
    for (int t = 0; t < 4; ++t) {
      short8 b = pW[((nh * 4 + t) * 4 + ks) * 64 + lane];
      acc[t] = __builtin_amdgcn_mfma_f32_16x16x32_bf16(a, b, acc[t], 0, 0, 0);
    }
  }

#pragma unroll
  for (int t = 0; t < 4; ++t) {
    int col = nh * 64 + t * 16 + l15;
    float bv = bias[col];
#pragma unroll
    for (int reg = 0; reg < 4; ++reg) {
      int row = mh * 16 + quad * 4 + reg;
      float v = acc[t][reg] + bv;
      size_t gi = (size_t)(row0 + row) * D + col;
      h[gi] = v;
      h_bf[gi] = f2bf(v);
    }
  }
}

// ================= fused: SpMM gather + gates + candidate + h update =================
// block: 256 thr (4 waves), 32 rows. Ping-pong h_bf buffers (gather reads h_bf_in of
// arbitrary rows; writes go to h_bf_out).
__global__ __launch_bounds__(256) void fused_step(
    const int* __restrict__ row_start, const int2* __restrict__ edata,
    const unsigned short* __restrict__ h_bf_in,
    const short* __restrict__ packZR, const short* __restrict__ packCW,
    const float* __restrict__ ugb, const float* __restrict__ rgb,
    float* __restrict__ h, unsigned short* __restrict__ h_bf_out) {
  __shared__ __align__(16) short sA[32 * 264];    // [row][c 0..255] = [h | m], stride 264 bf16
  __shared__ __align__(16) short sRH[32 * 136];   // [row][k], stride 136 bf16
  __shared__ float sZ[32 * 132];                  // [row][o], stride 132 f32

  const int tid = threadIdx.x;
  const int row0 = blockIdx.x * 32;
  const int wave = tid >> 6, lane = tid & 63;
  const unsigned int* hbu = (const unsigned int*)h_bf_in;

  // ---- stage h rows into sA[.., 0..127] ----
  {
    int r = tid >> 3, c2 = (tid & 7) * 2;
    const uint4* ph = (const uint4*)(h_bf_in + (size_t)(row0 + r) * D);
    *(uint4*)(sA + r * 264 + c2 * 8) = ph[c2];
    *(uint4*)(sA + r * 264 + (c2 + 1) * 8) = ph[c2 + 1];
  }

  // ---- SpMM gather: wave handles 8 rows; lane covers m cols 2*lane, 2*lane+1 ----
  for (int r8 = 0; r8 < 8; ++r8) {
    int row = row0 + wave * 8 + r8;
    int s0 = row_start[row];
    int n = row_start[row + 1] - s0;
    float a0 = 0.f, a1 = 0.f, b0 = 0.f, b1 = 0.f, c0 = 0.f, c1 = 0.f, d0 = 0.f, d1 = 0.f;
    int k = 0;
    for (; k + 3 < n; k += 4) {
      int2 e0 = edata[s0 + k], e1 = edata[s0 + k + 1], e2 = edata[s0 + k + 2], e3 = edata[s0 + k + 3];
      unsigned int u0 = hbu[(size_t)e0.x * 64 + lane];
      unsigned int u1 = hbu[(size_t)e1.x * 64 + lane];
      unsigned int u2 = hbu[(size_t)e2.x * 64 + lane];
      unsigned int u3 = hbu[(size_t)e3.x * 64 + lane];
      float w0 = __builtin_bit_cast(float, e0.y), w1 = __builtin_bit_cast(float, e1.y);
      float w2 = __builtin_bit_cast(float, e2.y), w3 = __builtin_bit_cast(float, e3.y);
      a0 += w0 * bflo(u0); a1 += w0 * bfhi(u0);
      b0 += w1 * bflo(u1); b1 += w1 * bfhi(u1);
      c0 += w2 * bflo(u2); c1 += w2 * bfhi(u2);
      d0 += w3 * bflo(u3); d1 += w3 * bfhi(u3);
    }
    for (; k < n; ++k) {
      int2 e = edata[s0 + k];
      unsigned int u = hbu[(size_t)e.x * 64 + lane];
      float w = __builtin_bit_cast(float, e.y);
      a0 += w * bflo(u); a1 += w * bfhi(u);
    }
    float m0 = (a0 + b0) + (c0 + d0);
    float m1 = (a1 + b1) + (c1 + d1);
    ((unsigned int*)sA)[(wave * 8 + r8) * 132 + 64 + lane] = pk2(m0, m1);
  }
  __syncthreads();

  const int quad = lane >> 4, l15 = lane & 15;
  const int mh = wave & 1, nh = wave >> 1;
  const int mrow = mh * 16 + l15;

  // ---- z/r: [32x256] @ [256x256] ----
  floatx4 acc[8];
  const floatx4 zero4 = {0.f, 0.f, 0.f, 0.f};
#pragma unroll
  for (int t = 0; t < 8; ++t) acc[t] = zero4;

  const short8* pB = (const short8*)packZR;
#pragma unroll
  for (int ks = 0; ks < 8; ++ks) {
    short8 a = *(const short8*)(sA + mrow * 264 + ks * 32 + quad * 8);
#pragma unroll
    for (int t = 0; t < 8; ++t) {
      short8 b = pB[((nh * 8 + t) * 8 + ks) * 64 + lane];
      acc[t] = __builtin_amdgcn_mfma_f32_16x16x32_bf16(a, b, acc[t], 0, 0, 0);
    }
  }

  if (nh == 0) {  // z -> sZ
#pragma unroll
    for (int t = 0; t < 8; ++t) {
      int col = t * 16 + l15;
      float bv = ugb[col];
#pragma unroll
      for (int reg = 0; reg < 4; ++reg) {
        int row = mh * 16 + quad * 4 + reg;
        sZ[row * 132 + col] = sig_f(acc[t][reg] + bv);
      }
    }
  } else {  // r -> rh in sRH
#pragma unroll
    for (int t = 0; t < 8; ++t) {
      int col = t * 16 + l15;
      float bv = rgb[col];
#pragma unroll
      for (int reg = 0; reg < 4; ++reg) {
        int row = mh * 16 + quad * 4 + reg;
        float rr = sig_f(acc[t][reg] + bv);
        float hv = bf2f((unsigned short)sA[row * 264 + col]);
        sRH[row * 136 + col] = (short)f2bf(rr * hv);
      }
    }
  }
  __syncthreads();

  // ---- cand: [32x128] @ [128x128] ----
  floatx4 acc2[4];
#pragma unroll
  for (int t = 0; t < 4; ++t) acc2[t] = zero4;

  const short8* pC = (const short8*)packCW;
#pragma unroll
  for (int ks = 0; ks < 4; ++ks) {
    short8 a = *(const short8*)(sRH + mrow * 136 + ks * 32 + quad * 8);
#pragma unroll
    for (int t = 0; t < 4; ++t) {
      short8 b = pC[((nh * 4 + t) * 4 + ks) * 64 + lane];
      acc2[t] = __builtin_amdgcn_mfma_f32_16x16x32_bf16(a, b, acc2[t], 0, 0, 0);
    }
  }

  // ---- epilogue: h = z*h + (1-z)*tanh(cand) ----
#pragma unroll
  for (int t = 0; t < 4; ++t) {
    int col = nh * 64 + t * 16 + l15;
#pragma unroll
    for (int reg = 0; reg < 4; ++reg) {
      int row = mh * 16 + quad * 4 + reg;
      float cand = tanh_f(acc2[t][reg]);
      float z = sZ[row * 132 + col];
      size_t gi = (size_t)(row0 + row) * D + col;
      float hold = h[gi];
      float hn = z * hold + (1.f - z) * cand;
      h[gi] = hn;
      h_bf_out[gi] = f2bf(hn);
    }
  }
}

extern "C" void kernel_launch(void* const* d_in, const int* in_sizes, int n_in,
                              void* d_out, int out_size, void* d_ws, size_t ws_size,
                              hipStream_t stream) {
  const float* input = (const float*)d_in[0];
  const int* erow    = (const int*)d_in[1];
  const int* ecol    = (const int*)d_in[2];
  const float* ew    = (const float*)d_in[3];
  const float* W     = (const float*)d_in[4];
  const float* bias  = (const float*)d_in[5];
  const float* CW    = (const float*)d_in[6];
  const float* ugW   = (const float*)d_in[7];
  const float* ugb   = (const float*)d_in[8];
  const float* rgW   = (const float*)d_in[9];
  const float* rgb   = (const float*)d_in[10];

  float* h = (float*)d_out;

  // ---- workspace carve-up (~65 MB) ----
  char* ws = (char*)d_ws;
  unsigned short* hbA  = (unsigned short*)ws; ws += (size_t)NN * D * 2;   // 25.6 MB
  unsigned short* hbB  = (unsigned short*)ws; ws += (size_t)NN * D * 2;   // 25.6 MB
  unsigned int* packZR = (unsigned int*)ws;   ws += 16 * 8 * 64 * 16;     // 128 KB
  unsigned int* packCW = (unsigned int*)ws;   ws += 8 * 4 * 64 * 16;      // 32 KB
  unsigned int* packW  = (unsigned int*)ws;   ws += 8 * 4 * 64 * 16;      // 32 KB
  int* cnt       = (int*)ws;                  ws += NN * sizeof(int);
  int* cursor    = (int*)ws;                  ws += NN * sizeof(int);
  int* row_start = (int*)ws;                  ws += (NN + 1) * sizeof(int);
  int* csum      = (int*)ws;                  ws += 512 * sizeof(int);
  int* coff      = (int*)ws;                  ws += 512 * sizeof(int);
  int2* edata    = (int2*)ws;                 ws += (size_t)EE * sizeof(int2);  // 12.8 MB

  // ---- CSR binning ----
  hipMemsetAsync(cnt, 0, NN * sizeof(int), stream);
  k_hist<<<(EE + 255) / 256, 256, 0, stream>>>(erow, cnt);
  k_chunk_sum<<<NCHUNK, 256, 0, stream>>>(cnt, csum);
  k_chunk_scan<<<1, 512, 0, stream>>>(csum, coff);
  k_row_start<<<NCHUNK, 256, 0, stream>>>(cnt, coff, row_start, cursor);
  k_scatter<<<(EE + 255) / 256, 256, 0, stream>>>(erow, ecol, ew, row_start, cursor, edata);

  // ---- weight packing + init ----
  k_pack_zr<<<128, 64, 0, stream>>>(ugW, rgW, packZR);
  k_pack_kn<<<32, 64, 0, stream>>>(CW, packCW);
  k_pack_kn<<<32, 64, 0, stream>>>(W, packW);
  init_mfma<<<NN / 32, 256, 0, stream>>>(input, (const short*)packW, bias, h, hbA);

  for (int step = 0; step < 3; ++step) {
    const unsigned short* hin = (step & 1) ? hbB : hbA;
    unsigned short* hout      = (step & 1) ? hbA : hbB;
    fused_step<<<NN / 32, 256, 0, stream>>>(row_start, edata, hin,
                                            (const short*)packZR, (const short*)packCW,
                                            ugb, rgb, h, hout);
  }
}

// Round 5
// 735.144 us; speedup vs baseline: 1.2304x; 1.2304x over previous
//
#include <hip/hip_runtime.h>
#include <math.h>

#define NN 100000
#define EE 1600000
#define D 128
#define NCHUNK ((NN + 255) / 256)   // 391

typedef __attribute__((ext_vector_type(8))) short short8;
typedef __attribute__((ext_vector_type(4))) float floatx4;

// ---------- helpers ----------
static __device__ __forceinline__ unsigned short f2bf(float f) {
  unsigned int u = __builtin_bit_cast(unsigned int, f);
  u = (u + 0x7fff + ((u >> 16) & 1)) >> 16;   // RNE
  return (unsigned short)u;
}
static __device__ __forceinline__ unsigned int pk2(float a, float b) {
  return (unsigned int)f2bf(a) | ((unsigned int)f2bf(b) << 16);
}
static __device__ __forceinline__ float bflo(unsigned int u) { return __builtin_bit_cast(float, u << 16); }
static __device__ __forceinline__ float bfhi(unsigned int u) { return __builtin_bit_cast(float, u & 0xffff0000u); }
static __device__ __forceinline__ float bf2f(unsigned short s) {
  return __builtin_bit_cast(float, (unsigned int)s << 16);
}
static __device__ __forceinline__ float sig_f(float x) { return 1.f / (1.f + __expf(-x)); }
static __device__ __forceinline__ float tanh_f(float x) {
  float e = __expf(2.f * x);
  return 1.f - 2.f / (e + 1.f);
}

// ================= CSR binning =================

__global__ __launch_bounds__(256) void k_hist(const int* __restrict__ erow, int* __restrict__ cnt) {
  int e = blockIdx.x * 256 + threadIdx.x;
  if (e < EE) atomicAdd(&cnt[erow[e]], 1);
}

__global__ __launch_bounds__(256) void k_chunk_sum(const int* __restrict__ cnt, int* __restrict__ csum) {
  __shared__ int s[256];
  int i = blockIdx.x * 256 + threadIdx.x;
  s[threadIdx.x] = (i < NN) ? cnt[i] : 0;
  __syncthreads();
  for (int d = 128; d > 0; d >>= 1) {
    if (threadIdx.x < d) s[threadIdx.x] += s[threadIdx.x + d];
    __syncthreads();
  }
  if (threadIdx.x == 0) csum[blockIdx.x] = s[0];
}

__global__ __launch_bounds__(512) void k_chunk_scan(const int* __restrict__ csum, int* __restrict__ coff) {
  __shared__ int s[512];
  int t = threadIdx.x;
  int v = (t < NCHUNK) ? csum[t] : 0;
  s[t] = v;
  __syncthreads();
  for (int d = 1; d < 512; d <<= 1) {
    int tv = (t >= d) ? s[t - d] : 0;
    __syncthreads();
    s[t] += tv;
    __syncthreads();
  }
  if (t < NCHUNK) coff[t] = s[t] - v;  // exclusive
}

__global__ __launch_bounds__(256) void k_row_start(const int* __restrict__ cnt, const int* __restrict__ coff,
                                                   int* __restrict__ row_start, int* __restrict__ cursor) {
  __shared__ int s[256];
  int i = blockIdx.x * 256 + threadIdx.x;
  int v = (i < NN) ? cnt[i] : 0;
  s[threadIdx.x] = v;
  __syncthreads();
  for (int d = 1; d < 256; d <<= 1) {
    int tv = (threadIdx.x >= d) ? s[threadIdx.x - d] : 0;
    __syncthreads();
    s[threadIdx.x] += tv;
    __syncthreads();
  }
  int excl = s[threadIdx.x] - v + coff[blockIdx.x];
  if (i < NN) { row_start[i] = excl; cursor[i] = 0; }
  if (i == NN - 1) row_start[NN] = excl + v;
}

__global__ __launch_bounds__(256) void k_scatter(const int* __restrict__ erow, const int* __restrict__ ecol,
                                                 const float* __restrict__ ew,
                                                 const int* __restrict__ row_start, int* __restrict__ cursor,
                                                 int2* __restrict__ edata) {
  int e = blockIdx.x * 256 + threadIdx.x;
  if (e >= EE) return;
  int r = erow[e];
  int pos = row_start[r] + atomicAdd(&cursor[r], 1);
  int2 out;
  out.x = ecol[e];
  out.y = __builtin_bit_cast(int, ew[e]);
  edata[pos] = out;
}

// ================= weight packing into MFMA B-fragment order =================
// b_frag[lane][j] = W_zr[o = nt*16 + (lane&15)][c = ks*32 + (lane>>4)*8 + j]
__global__ __launch_bounds__(64) void k_pack_zr(const float* __restrict__ ugW, const float* __restrict__ rgW,
                                                unsigned int* __restrict__ packZR) {
  int g = blockIdx.x;           // g = nt*8 + ks, nt 0..15, ks 0..7
  int nt = g >> 3, ks = g & 7;
  int lane = threadIdx.x;
  int o = nt * 16 + (lane & 15);
  int c0 = ks * 32 + (lane >> 4) * 8;
  const float* src = (o < 128 ? ugW + (size_t)o * 256 : rgW + (size_t)(o - 128) * 256) + c0;
  float4 f0 = ((const float4*)src)[0];
  float4 f1 = ((const float4*)src)[1];
  uint4 out;
  out.x = pk2(f0.x, f0.y);
  out.y = pk2(f0.z, f0.w);
  out.z = pk2(f1.x, f1.y);
  out.w = pk2(f1.z, f1.w);
  ((uint4*)packZR)[g * 64 + lane] = out;
}

// b_frag[lane][j] = M[k = ks*32 + (lane>>4)*8 + j][n = nt*16 + (lane&15)]  (M row-major [k][128])
__global__ __launch_bounds__(64) void k_pack_kn(const float* __restrict__ M, unsigned int* __restrict__ pack) {
  int g = blockIdx.x;           // g = nt*4 + ks, nt 0..7, ks 0..3
  int nt = g >> 2, ks = g & 3;
  int lane = threadIdx.x;
  int n = nt * 16 + (lane & 15);
  int k0 = ks * 32 + (lane >> 4) * 8;
  unsigned short v[8];
#pragma unroll
  for (int j = 0; j < 8; ++j) v[j] = f2bf(M[(size_t)(k0 + j) * 128 + n]);
  uint4 out;
  out.x = (unsigned int)v[0] | ((unsigned int)v[1] << 16);
  out.y = (unsigned int)v[2] | ((unsigned int)v[3] << 16);
  out.z = (unsigned int)v[4] | ((unsigned int)v[5] << 16);
  out.w = (unsigned int)v[6] | ((unsigned int)v[7] << 16);
  ((uint4*)pack)[g * 64 + lane] = out;
}

// ================= h0 = X @ W + b via MFMA (bf16 master only) =================
__global__ __launch_bounds__(256) void init_mfma(
    const float* __restrict__ X, const short* __restrict__ packW, const float* __restrict__ bias,
    unsigned short* __restrict__ h_bf) {
  __shared__ __align__(16) short sX[32 * 136];   // [row][k], stride 136 bf16
  const int tid = threadIdx.x;
  const int row0 = blockIdx.x * 32;

  {
    int r = tid >> 3, ch = tid & 7;              // 16-float chunk per thread
    const float4* px = (const float4*)(X + (size_t)(row0 + r) * D + ch * 16);
    float4 f0 = px[0], f1 = px[1], f2 = px[2], f3 = px[3];
    uint4 o0, o1;
    o0.x = pk2(f0.x, f0.y); o0.y = pk2(f0.z, f0.w);
    o0.z = pk2(f1.x, f1.y); o0.w = pk2(f1.z, f1.w);
    o1.x = pk2(f2.x, f2.y); o1.y = pk2(f2.z, f2.w);
    o1.z = pk2(f3.x, f3.y); o1.w = pk2(f3.z, f3.w);
    *(uint4*)(sX + r * 136 + ch * 16) = o0;
    *(uint4*)(sX + r * 136 + ch * 16 + 8) = o1;
  }
  __syncthreads();

  const int wave = tid >> 6, lane = tid & 63;
  const int quad = lane >> 4, l15 = lane & 15;
  const int mh = wave & 1, nh = wave >> 1;
  const int mrow = mh * 16 + l15;

  floatx4 acc[4];
  const floatx4 zero4 = {0.f, 0.f, 0.f, 0.f};
#pragma unroll
  for (int t = 0; t < 4; ++t) acc[t] = zero4;

  const short8* pW = (const short8*)packW;
#pragma unroll
  for (int ks = 0; ks < 4; ++ks) {
    short8 a = *(const short8*)(sX + mrow * 136 + ks * 32 + quad * 8);
#pragma unroll
    for (int t = 0; t < 4; ++t) {
      short8 b = pW[((nh * 4 + t) * 4 + ks) * 64 + lane];
      acc[t] = __builtin_amdgcn_mfma_f32_16x16x32_bf16(a, b, acc[t], 0, 0, 0);
    }
  }

#pragma unroll
  for (int t = 0; t < 4; ++t) {
    int col = nh * 64 + t * 16 + l15;
    float bv = bias[col];
#pragma unroll
    for (int reg = 0; reg < 4; ++reg) {
      int row = mh * 16 + quad * 4 + reg;
      h_bf[(size_t)(row0 + row) * D + col] = f2bf(acc[t][reg] + bv);
    }
  }
}

// ================= SpMM: m_bf[row] = sum_e w_e * h_bf[col_e] (wave/row, max occupancy) =================
__global__ __launch_bounds__(256) void spmm_gather_bf(
    const int* __restrict__ row_start, const int2* __restrict__ edata,
    const unsigned int* __restrict__ h_bf_u, unsigned int* __restrict__ m_bf_u) {
  const int lane = threadIdx.x & 63;
  const int row = blockIdx.x * 4 + (threadIdx.x >> 6);
  if (row >= NN) return;
  const int s0 = row_start[row];
  const int n = row_start[row + 1] - s0;

  float a0 = 0.f, a1 = 0.f, b0 = 0.f, b1 = 0.f, c0 = 0.f, c1 = 0.f, d0 = 0.f, d1 = 0.f;
  int k = 0;
  for (; k + 3 < n; k += 4) {
    int2 e0 = edata[s0 + k], e1 = edata[s0 + k + 1], e2 = edata[s0 + k + 2], e3 = edata[s0 + k + 3];
    unsigned int u0 = h_bf_u[(size_t)e0.x * 64 + lane];
    unsigned int u1 = h_bf_u[(size_t)e1.x * 64 + lane];
    unsigned int u2 = h_bf_u[(size_t)e2.x * 64 + lane];
    unsigned int u3 = h_bf_u[(size_t)e3.x * 64 + lane];
    float w0 = __builtin_bit_cast(float, e0.y), w1 = __builtin_bit_cast(float, e1.y);
    float w2 = __builtin_bit_cast(float, e2.y), w3 = __builtin_bit_cast(float, e3.y);
    a0 += w0 * bflo(u0); a1 += w0 * bfhi(u0);
    b0 += w1 * bflo(u1); b1 += w1 * bfhi(u1);
    c0 += w2 * bflo(u2); c1 += w2 * bfhi(u2);
    d0 += w3 * bflo(u3); d1 += w3 * bfhi(u3);
  }
  for (; k < n; ++k) {
    int2 e = edata[s0 + k];
    unsigned int u = h_bf_u[(size_t)e.x * 64 + lane];
    float w = __builtin_bit_cast(float, e.y);
    a0 += w * bflo(u); a1 += w * bfhi(u);
  }
  m_bf_u[(size_t)row * 64 + lane] = pk2((a0 + b0) + (c0 + d0), (a1 + b1) + (c1 + d1));
}

// ================= gates + candidate + h update, bf16 MFMA =================
// block: 256 thr (4 waves), 32 rows. h master is bf16; fp32 written to d_out on last step only.
__global__ __launch_bounds__(256) void gate_mfma(
    const unsigned short* __restrict__ h_bf, const unsigned short* __restrict__ m_bf,
    const short* __restrict__ packZR, const short* __restrict__ packCW,
    const float* __restrict__ ugb, const float* __restrict__ rgb,
    unsigned short* __restrict__ h_bf_out, float* __restrict__ h_f32_out, int last) {
  __shared__ __align__(16) short sA[32 * 264];           // [row][c 0..255] = [h | m]  (16.9 KB)
  __shared__ __align__(16) short sRH[32 * 136];          // [row][k]                  (8.7 KB)
  __shared__ unsigned short sZ16[32 * 136];              // z in u16 fixed point      (8.7 KB)

  const int tid = threadIdx.x;
  const int row0 = blockIdx.x * 32;

  // ---- stage [h | m] bf16 tile ----
  for (int idx = tid; idx < 512; idx += 256) {
    int r = idx >> 4, ch = idx & 15;
    const uint4* ph = (const uint4*)(h_bf + (size_t)(row0 + r) * D);
    const uint4* pm = (const uint4*)(m_bf + (size_t)(row0 + r) * D);
    *(uint4*)(sA + r * 264 + ch * 8) = ph[ch];
    *(uint4*)(sA + r * 264 + 128 + ch * 8) = pm[ch];
  }
  __syncthreads();

  const int wave = tid >> 6, lane = tid & 63;
  const int quad = lane >> 4, l15 = lane & 15;
  const int mh = wave & 1, nh = wave >> 1;
  const int mrow = mh * 16 + l15;

  // ---- z/r: [32x256] @ [256x256] ----
  floatx4 acc[8];
  const floatx4 zero4 = {0.f, 0.f, 0.f, 0.f};
#pragma unroll
  for (int t = 0; t < 8; ++t) acc[t] = zero4;

  const short8* pB = (const short8*)packZR;
#pragma unroll
  for (int ks = 0; ks < 8; ++ks) {
    short8 a = *(const short8*)(sA + mrow * 264 + ks * 32 + quad * 8);
#pragma unroll
    for (int t = 0; t < 8; ++t) {
      short8 b = pB[((nh * 8 + t) * 8 + ks) * 64 + lane];
      acc[t] = __builtin_amdgcn_mfma_f32_16x16x32_bf16(a, b, acc[t], 0, 0, 0);
    }
  }

  if (nh == 0) {  // z -> sZ16 (u16 fixed point; |err| ~ 7.6e-6)
#pragma unroll
    for (int t = 0; t < 8; ++t) {
      int col = t * 16 + l15;
      float bv = ugb[col];
#pragma unroll
      for (int reg = 0; reg < 4; ++reg) {
        int row = mh * 16 + quad * 4 + reg;
        float z = sig_f(acc[t][reg] + bv);
        sZ16[row * 136 + col] = (unsigned short)__float2uint_rn(z * 65535.f);
      }
    }
  } else {  // r -> rh in sRH
#pragma unroll
    for (int t = 0; t < 8; ++t) {
      int col = t * 16 + l15;
      float bv = rgb[col];
#pragma unroll
      for (int reg = 0; reg < 4; ++reg) {
        int row = mh * 16 + quad * 4 + reg;
        float rr = sig_f(acc[t][reg] + bv);
        float hv = bf2f((unsigned short)sA[row * 264 + col]);
        sRH[row * 136 + col] = (short)f2bf(rr * hv);
      }
    }
  }
  __syncthreads();

  // ---- cand: [32x128] @ [128x128] ----
  floatx4 acc2[4];
#pragma unroll
  for (int t = 0; t < 4; ++t) acc2[t] = zero4;

  const short8* pC = (const short8*)packCW;
#pragma unroll
  for (int ks = 0; ks < 4; ++ks) {
    short8 a = *(const short8*)(sRH + mrow * 136 + ks * 32 + quad * 8);
#pragma unroll
    for (int t = 0; t < 4; ++t) {
      short8 b = pC[((nh * 4 + t) * 4 + ks) * 64 + lane];
      acc2[t] = __builtin_amdgcn_mfma_f32_16x16x32_bf16(a, b, acc2[t], 0, 0, 0);
    }
  }

  // ---- epilogue: h = z*h + (1-z)*tanh(cand); hold comes from the LDS h-tile ----
#pragma unroll
  for (int t = 0; t < 4; ++t) {
    int col = nh * 64 + t * 16 + l15;
#pragma unroll
    for (int reg = 0; reg < 4; ++reg) {
      int row = mh * 16 + quad * 4 + reg;
      float cand = tanh_f(acc2[t][reg]);
      float z = (float)sZ16[row * 136 + col] * (1.f / 65535.f);
      float hold = bf2f((unsigned short)sA[row * 264 + col]);
      float hn = z * hold + (1.f - z) * cand;
      size_t gi = (size_t)(row0 + row) * D + col;
      if (last) h_f32_out[gi] = hn;
      else h_bf_out[gi] = f2bf(hn);
    }
  }
}

extern "C" void kernel_launch(void* const* d_in, const int* in_sizes, int n_in,
                              void* d_out, int out_size, void* d_ws, size_t ws_size,
                              hipStream_t stream) {
  const float* input = (const float*)d_in[0];
  const int* erow    = (const int*)d_in[1];
  const int* ecol    = (const int*)d_in[2];
  const float* ew    = (const float*)d_in[3];
  const float* W     = (const float*)d_in[4];
  const float* bias  = (const float*)d_in[5];
  const float* CW    = (const float*)d_in[6];
  const float* ugW   = (const float*)d_in[7];
  const float* ugb   = (const float*)d_in[8];
  const float* rgW   = (const float*)d_in[9];
  const float* rgb   = (const float*)d_in[10];

  float* h_out = (float*)d_out;

  // ---- workspace carve-up (~65 MB) ----
  char* ws = (char*)d_ws;
  unsigned short* h_bf = (unsigned short*)ws; ws += (size_t)NN * D * 2;   // 25.6 MB
  unsigned short* m_bf = (unsigned short*)ws; ws += (size_t)NN * D * 2;   // 25.6 MB
  unsigned int* packZR = (unsigned int*)ws;   ws += 16 * 8 * 64 * 16;     // 128 KB
  unsigned int* packCW = (unsigned int*)ws;   ws += 8 * 4 * 64 * 16;      // 32 KB
  unsigned int* packW  = (unsigned int*)ws;   ws += 8 * 4 * 64 * 16;      // 32 KB
  int* cnt       = (int*)ws;                  ws += NN * sizeof(int);
  int* cursor    = (int*)ws;                  ws += NN * sizeof(int);
  int* row_start = (int*)ws;                  ws += (NN + 1) * sizeof(int);
  int* csum      = (int*)ws;                  ws += 512 * sizeof(int);
  int* coff      = (int*)ws;                  ws += 512 * sizeof(int);
  int2* edata    = (int2*)ws;                 ws += (size_t)EE * sizeof(int2);  // 12.8 MB

  // ---- CSR binning ----
  hipMemsetAsync(cnt, 0, NN * sizeof(int), stream);
  k_hist<<<(EE + 255) / 256, 256, 0, stream>>>(erow, cnt);
  k_chunk_sum<<<NCHUNK, 256, 0, stream>>>(cnt, csum);
  k_chunk_scan<<<1, 512, 0, stream>>>(csum, coff);
  k_row_start<<<NCHUNK, 256, 0, stream>>>(cnt, coff, row_start, cursor);
  k_scatter<<<(EE + 255) / 256, 256, 0, stream>>>(erow, ecol, ew, row_start, cursor, edata);

  // ---- weight packing + init ----
  k_pack_zr<<<128, 64, 0, stream>>>(ugW, rgW, packZR);
  k_pack_kn<<<32, 64, 0, stream>>>(CW, packCW);
  k_pack_kn<<<32, 64, 0, stream>>>(W, packW);
  init_mfma<<<NN / 32, 256, 0, stream>>>(input, (const short*)packW, bias, h_bf);

  for (int step = 0; step < 3; ++step) {
    spmm_gather_bf<<<(NN + 3) / 4, 256, 0, stream>>>(row_start, edata,
                                                     (const unsigned int*)h_bf, (unsigned int*)m_bf);
    gate_mfma<<<NN / 32, 256, 0, stream>>>(h_bf, m_bf, (const short*)packZR, (const short*)packCW,
                                           ugb, rgb, h_bf, h_out, step == 2 ? 1 : 0);
  }
}

// Round 7
// 590.599 us; speedup vs baseline: 1.5315x; 1.2447x over previous
//
#include <hip/hip_runtime.h>
#include <math.h>

#define NN 100000
#define EE 1600000
#define D 128
#define NB 782            // buckets of 128 rows: ceil(100000/128)
#define SBLK 98           // scatter blocks
#define EPB 16384         // edges per scatter block (98*16384 >= EE)

typedef __attribute__((ext_vector_type(8))) short short8;
typedef __attribute__((ext_vector_type(4))) float floatx4;

// ---------- helpers ----------
static __device__ __forceinline__ unsigned short f2bf(float f) {
  unsigned int u = __builtin_bit_cast(unsigned int, f);
  u = (u + 0x7fff + ((u >> 16) & 1)) >> 16;   // RNE
  return (unsigned short)u;
}
static __device__ __forceinline__ unsigned int pk2(float a, float b) {
  return (unsigned int)f2bf(a) | ((unsigned int)f2bf(b) << 16);
}
static __device__ __forceinline__ float bflo(unsigned int u) { return __builtin_bit_cast(float, u << 16); }
static __device__ __forceinline__ float bfhi(unsigned int u) { return __builtin_bit_cast(float, u & 0xffff0000u); }
static __device__ __forceinline__ float bf2f(unsigned short s) {
  return __builtin_bit_cast(float, (unsigned int)s << 16);
}
static __device__ __forceinline__ float sig_f(float x) { return 1.f / (1.f + __expf(-x)); }
static __device__ __forceinline__ float tanh_f(float x) {
  float e = __expf(2.f * x);
  return 1.f - 2.f / (e + 1.f);
}

// ================= CSR build: bucket multisplit with single-owner writes =================

// Pass 1: per-(block,bucket) counts via LDS histogram
__global__ __launch_bounds__(1024) void b_count(const int* __restrict__ erow, int* __restrict__ cnt_pb) {
  __shared__ int s[NB];
  const int tid = threadIdx.x;
  for (int b = tid; b < NB; b += 1024) s[b] = 0;
  __syncthreads();
  const int base = blockIdx.x * EPB;
#pragma unroll
  for (int i = 0; i < 16; ++i) {
    int idx = base + i * 1024 + tid;
    if (idx < EE) atomicAdd(&s[erow[idx] >> 7], 1);
  }
  __syncthreads();
  for (int b = tid; b < NB; b += 1024) cnt_pb[blockIdx.x * NB + b] = s[b];
}

// Pass 2 (1 block): bucket totals -> exclusive bucket_off; per-(block,bucket) bases
__global__ __launch_bounds__(1024) void b_scan(const int* __restrict__ cnt_pb,
                                               int* __restrict__ base_pb, int* __restrict__ bucket_off) {
  __shared__ int s[1024];
  const int b = threadIdx.x;
  int tot = 0;
  if (b < NB) {
    for (int j = 0; j < SBLK; ++j) tot += cnt_pb[j * NB + b];
  }
  s[b] = tot;
  __syncthreads();
  for (int d = 1; d < 1024; d <<= 1) {
    int v = (b >= d) ? s[b - d] : 0;
    __syncthreads();
    s[b] += v;
    __syncthreads();
  }
  int excl = s[b] - tot;
  if (b < NB) {
    bucket_off[b] = excl;
    int run = excl;
    for (int j = 0; j < SBLK; ++j) { base_pb[j * NB + b] = run; run += cnt_pb[j * NB + b]; }
  }
  if (b == NB - 1) bucket_off[NB] = excl + tot;
}

// Pass 3: scatter into bucket arena; block writes per bucket are contiguous (write-combined)
__global__ __launch_bounds__(1024) void b_scatter(const int* __restrict__ erow, const int* __restrict__ ecol,
                                                  const float* __restrict__ ew,
                                                  const int* __restrict__ base_pb, int2* __restrict__ arena) {
  __shared__ int cur[NB];
  const int tid = threadIdx.x;
  for (int b = tid; b < NB; b += 1024) cur[b] = base_pb[blockIdx.x * NB + b];
  __syncthreads();
  const int base = blockIdx.x * EPB;
#pragma unroll
  for (int i = 0; i < 16; ++i) {
    int idx = base + i * 1024 + tid;
    if (idx < EE) {
      int r = erow[idx];
      int pos = atomicAdd(&cur[r >> 7], 1);
      int2 v;
      v.x = ecol[idx] | ((r & 127) << 24);   // col fits 17 bits; row-local 7 bits in 24..30
      v.y = __builtin_bit_cast(int, ew[idx]);
      arena[pos] = v;
    }
  }
}

// Pass 4: counting-sort within bucket -> final CSR (single-owner contiguous region) + row_start
__global__ __launch_bounds__(256) void b_sort(const int* __restrict__ bucket_off, const int2* __restrict__ arena,
                                              int2* __restrict__ edata, int* __restrict__ row_start) {
  __shared__ int rcnt[128];
  __shared__ int rcur[128];
  const int b = blockIdx.x;
  const int tid = threadIdx.x;
  const int lo = bucket_off[b], hi = bucket_off[b + 1];

  if (tid < 128) rcnt[tid] = 0;
  __syncthreads();
  for (int i = lo + tid; i < hi; i += 256) atomicAdd(&rcnt[(arena[i].x >> 24) & 127], 1);
  __syncthreads();
  int myc = (tid < 128) ? rcnt[tid] : 0;
  for (int d = 1; d < 128; d <<= 1) {
    int v = (tid < 128 && tid >= d) ? rcnt[tid - d] : 0;
    __syncthreads();
    if (tid < 128) rcnt[tid] += v;
    __syncthreads();
  }
  if (tid < 128) {
    int excl = rcnt[tid] - myc;
    rcur[tid] = lo + excl;
    int gr = b * 128 + tid;
    if (gr < NN) row_start[gr] = lo + excl;
  }
  if (b == NB - 1 && tid == 0) row_start[NN] = hi;
  __syncthreads();

  for (int i = lo + tid; i < hi; i += 256) {
    int2 v = arena[i];
    int rl = (v.x >> 24) & 127;
    int pos = atomicAdd(&rcur[rl], 1);
    int2 o;
    o.x = v.x & 0x00FFFFFF;
    o.y = v.y;
    edata[pos] = o;
  }
}

// ================= weight packing into MFMA B-fragment order =================
__global__ __launch_bounds__(64) void k_pack_zr(const float* __restrict__ ugW, const float* __restrict__ rgW,
                                                unsigned int* __restrict__ packZR) {
  int g = blockIdx.x;           // g = nt*8 + ks, nt 0..15, ks 0..7
  int nt = g >> 3, ks = g & 7;
  int lane = threadIdx.x;
  int o = nt * 16 + (lane & 15);
  int c0 = ks * 32 + (lane >> 4) * 8;
  const float* src = (o < 128 ? ugW + (size_t)o * 256 : rgW + (size_t)(o - 128) * 256) + c0;
  float4 f0 = ((const float4*)src)[0];
  float4 f1 = ((const float4*)src)[1];
  uint4 out;
  out.x = pk2(f0.x, f0.y);
  out.y = pk2(f0.z, f0.w);
  out.z = pk2(f1.x, f1.y);
  out.w = pk2(f1.z, f1.w);
  ((uint4*)packZR)[g * 64 + lane] = out;
}

__global__ __launch_bounds__(64) void k_pack_kn(const float* __restrict__ M, unsigned int* __restrict__ pack) {
  int g = blockIdx.x;           // g = nt*4 + ks, nt 0..7, ks 0..3
  int nt = g >> 2, ks = g & 3;
  int lane = threadIdx.x;
  int n = nt * 16 + (lane & 15);
  int k0 = ks * 32 + (lane >> 4) * 8;
  unsigned short v[8];
#pragma unroll
  for (int j = 0; j < 8; ++j) v[j] = f2bf(M[(size_t)(k0 + j) * 128 + n]);
  uint4 out;
  out.x = (unsigned int)v[0] | ((unsigned int)v[1] << 16);
  out.y = (unsigned int)v[2] | ((unsigned int)v[3] << 16);
  out.z = (unsigned int)v[4] | ((unsigned int)v[5] << 16);
  out.w = (unsigned int)v[6] | ((unsigned int)v[7] << 16);
  ((uint4*)pack)[g * 64 + lane] = out;
}

// ================= h0 = X @ W + b via MFMA (bf16 master) =================
__global__ __launch_bounds__(256) void init_mfma(
    const float* __restrict__ X, const short* __restrict__ packW, const float* __restrict__ bias,
    unsigned short* __restrict__ h_bf) {
  __shared__ __align__(16) short sX[32 * 136];
  const int tid = threadIdx.x;
  const int row0 = blockIdx.x * 32;

  {
    int r = tid >> 3, ch = tid & 7;
    const float4* px = (const float4*)(X + (size_t)(row0 + r) * D + ch * 16);
    float4 f0 = px[0], f1 = px[1], f2 = px[2], f3 = px[3];
    uint4 o0, o1;
    o0.x = pk2(f0.x, f0.y); o0.y = pk2(f0.z, f0.w);
    o0.z = pk2(f1.x, f1.y); o0.w = pk2(f1.z, f1.w);
    o1.x = pk2(f2.x, f2.y); o1.y = pk2(f2.z, f2.w);
    o1.z = pk2(f3.x, f3.y); o1.w = pk2(f3.z, f3.w);
    *(uint4*)(sX + r * 136 + ch * 16) = o0;
    *(uint4*)(sX + r * 136 + ch * 16 + 8) = o1;
  }
  __syncthreads();

  const int wave = tid >> 6, lane = tid & 63;
  const int quad = lane >> 4, l15 = lane & 15;
  const int mh = wave & 1, nh = wave >> 1;
  const int mrow = mh * 16 + l15;

  floatx4 acc[4];
  const floatx4 zero4 = {0.f, 0.f, 0.f, 0.f};
#pragma unroll
  for (int t = 0; t < 4; ++t) acc[t] = zero4;

  const short8* pW = (const short8*)packW;
#pragma unroll
  for (int ks = 0; ks < 4; ++ks) {
    short8 a = *(const short8*)(sX + mrow * 136 + ks * 32 + quad * 8);
#pragma unroll
    for (int t = 0; t < 4; ++t) {
      short8 b = pW[((nh * 4 + t) * 4 + ks) * 64 + lane];
      acc[t] = __builtin_amdgcn_mfma_f32_16x16x32_bf16(a, b, acc[t], 0, 0, 0);
    }
  }

#pragma unroll
  for (int t = 0; t < 4; ++t) {
    int col = nh * 64 + t * 16 + l15;
    float bv = bias[col];
#pragma unroll
    for (int reg = 0; reg < 4; ++reg) {
      int row = mh * 16 + quad * 4 + reg;
      h_bf[(size_t)(row0 + row) * D + col] = f2bf(acc[t][reg] + bv);
    }
  }
}

// ================= SpMM: wave/row, 16 lanes x dwordx4 per edge, 4 edges per pass =================
// h row = 128 bf16 = 256 B = 16 uint4  -> row stride in uint4 units is 16.
__global__ __launch_bounds__(256) void spmm_gather_bf(
    const int* __restrict__ row_start, const int2* __restrict__ edata,
    const uint4* __restrict__ h4, uint4* __restrict__ m4) {
  const int lane = threadIdx.x & 63;
  const int row = blockIdx.x * 4 + (threadIdx.x >> 6);
  if (row >= NN) return;
  const int s0 = row_start[row];
  const int end = row_start[row + 1];
  const int sub = lane >> 4, li = lane & 15;

  float acc[8];
#pragma unroll
  for (int j = 0; j < 8; ++j) acc[j] = 0.f;

  int kk = s0;
  for (; kk + 8 <= end; kk += 8) {            // both groups' edges in-range: no guards
    int2 e0 = edata[kk + sub];
    int2 e1 = edata[kk + 4 + sub];
    uint4 h0 = h4[(size_t)e0.x * 16 + li];
    uint4 h1 = h4[(size_t)e1.x * 16 + li];
    float w0 = __builtin_bit_cast(float, e0.y);
    float w1 = __builtin_bit_cast(float, e1.y);
    acc[0] += w0 * bflo(h0.x); acc[1] += w0 * bfhi(h0.x);
    acc[2] += w0 * bflo(h0.y); acc[3] += w0 * bfhi(h0.y);
    acc[4] += w0 * bflo(h0.z); acc[5] += w0 * bfhi(h0.z);
    acc[6] += w0 * bflo(h0.w); acc[7] += w0 * bfhi(h0.w);
    acc[0] += w1 * bflo(h1.x); acc[1] += w1 * bfhi(h1.x);
    acc[2] += w1 * bflo(h1.y); acc[3] += w1 * bfhi(h1.y);
    acc[4] += w1 * bflo(h1.z); acc[5] += w1 * bfhi(h1.z);
    acc[6] += w1 * bflo(h1.w); acc[7] += w1 * bfhi(h1.w);
  }
  for (; kk < end; kk += 4) {
    int e = kk + sub;
    if (e < end) {
      int2 ed = edata[e];
      uint4 hv = h4[(size_t)ed.x * 16 + li];
      float w = __builtin_bit_cast(float, ed.y);
      acc[0] += w * bflo(hv.x); acc[1] += w * bfhi(hv.x);
      acc[2] += w * bflo(hv.y); acc[3] += w * bfhi(hv.y);
      acc[4] += w * bflo(hv.z); acc[5] += w * bfhi(hv.z);
      acc[6] += w * bflo(hv.w); acc[7] += w * bfhi(hv.w);
    }
  }

  // reduce across the 4 sub-groups (lanes li, li+16, li+32, li+48 share columns)
#pragma unroll
  for (int j = 0; j < 8; ++j) acc[j] += __shfl_xor(acc[j], 16, 64);
#pragma unroll
  for (int j = 0; j < 8; ++j) acc[j] += __shfl_xor(acc[j], 32, 64);

  if (sub == 0) {
    uint4 o;
    o.x = pk2(acc[0], acc[1]);
    o.y = pk2(acc[2], acc[3]);
    o.z = pk2(acc[4], acc[5]);
    o.w = pk2(acc[6], acc[7]);
    m4[(size_t)row * 16 + li] = o;
  }
}

// ================= gates + candidate + h update, bf16 MFMA =================
__global__ __launch_bounds__(256) void gate_mfma(
    const unsigned short* __restrict__ h_bf, const unsigned short* __restrict__ m_bf,
    const short* __restrict__ packZR, const short* __restrict__ packCW,
    const float* __restrict__ ugb, const float* __restrict__ rgb,
    unsigned short* __restrict__ h_bf_out, float* __restrict__ h_f32_out, int last) {
  __shared__ __align__(16) short sA[32 * 264];           // [row][c] = [h | m]
  __shared__ __align__(16) short sRH[32 * 136];
  __shared__ unsigned short sZ16[32 * 136];

  const int tid = threadIdx.x;
  const int row0 = blockIdx.x * 32;

  for (int idx = tid; idx < 512; idx += 256) {
    int r = idx >> 4, ch = idx & 15;
    const uint4* ph = (const uint4*)(h_bf + (size_t)(row0 + r) * D);
    const uint4* pm = (const uint4*)(m_bf + (size_t)(row0 + r) * D);
    *(uint4*)(sA + r * 264 + ch * 8) = ph[ch];
    *(uint4*)(sA + r * 264 + 128 + ch * 8) = pm[ch];
  }
  __syncthreads();

  const int wave = tid >> 6, lane = tid & 63;
  const int quad = lane >> 4, l15 = lane & 15;
  const int mh = wave & 1, nh = wave >> 1;
  const int mrow = mh * 16 + l15;

  floatx4 acc[8];
  const floatx4 zero4 = {0.f, 0.f, 0.f, 0.f};
#pragma unroll
  for (int t = 0; t < 8; ++t) acc[t] = zero4;

  const short8* pB = (const short8*)packZR;
#pragma unroll
  for (int ks = 0; ks < 8; ++ks) {
    short8 a = *(const short8*)(sA + mrow * 264 + ks * 32 + quad * 8);
#pragma unroll
    for (int t = 0; t < 8; ++t) {
      short8 b = pB[((nh * 8 + t) * 8 + ks) * 64 + lane];
      acc[t] = __builtin_amdgcn_mfma_f32_16x16x32_bf16(a, b, acc[t], 0, 0, 0);
    }
  }

  if (nh == 0) {
#pragma unroll
    for (int t = 0; t < 8; ++t) {
      int col = t * 16 + l15;
      float bv = ugb[col];
#pragma unroll
      for (int reg = 0; reg < 4; ++reg) {
        int row = mh * 16 + quad * 4 + reg;
        float z = sig_f(acc[t][reg] + bv);
        sZ16[row * 136 + col] = (unsigned short)__float2uint_rn(z * 65535.f);
      }
    }
  } else {
#pragma unroll
    for (int t = 0; t < 8; ++t) {
      int col = t * 16 + l15;
      float bv = rgb[col];
#pragma unroll
      for (int reg = 0; reg < 4; ++reg) {
        int row = mh * 16 + quad * 4 + reg;
        float rr = sig_f(acc[t][reg] + bv);
        float hv = bf2f((unsigned short)sA[row * 264 + col]);
        sRH[row * 136 + col] = (short)f2bf(rr * hv);
      }
    }
  }
  __syncthreads();

  floatx4 acc2[4];
#pragma unroll
  for (int t = 0; t < 4; ++t) acc2[t] = zero4;

  const short8* pC = (const short8*)packCW;
#pragma unroll
  for (int ks = 0; ks < 4; ++ks) {
    short8 a = *(const short8*)(sRH + mrow * 136 + ks * 32 + quad * 8);
#pragma unroll
    for (int t = 0; t < 4; ++t) {
      short8 b = pC[((nh * 4 + t) * 4 + ks) * 64 + lane];
      acc2[t] = __builtin_amdgcn_mfma_f32_16x16x32_bf16(a, b, acc2[t], 0, 0, 0);
    }
  }

#pragma unroll
  for (int t = 0; t < 4; ++t) {
    int col = nh * 64 + t * 16 + l15;
#pragma unroll
    for (int reg = 0; reg < 4; ++reg) {
      int row = mh * 16 + quad * 4 + reg;
      float cand = tanh_f(acc2[t][reg]);
      float z = (float)sZ16[row * 136 + col] * (1.f / 65535.f);
      float hold = bf2f((unsigned short)sA[row * 264 + col]);
      float hn = z * hold + (1.f - z) * cand;
      size_t gi = (size_t)(row0 + row) * D + col;
      if (last) h_f32_out[gi] = hn;
      else h_bf_out[gi] = f2bf(hn);
    }
  }
}

extern "C" void kernel_launch(void* const* d_in, const int* in_sizes, int n_in,
                              void* d_out, int out_size, void* d_ws, size_t ws_size,
                              hipStream_t stream) {
  const float* input = (const float*)d_in[0];
  const int* erow    = (const int*)d_in[1];
  const int* ecol    = (const int*)d_in[2];
  const float* ew    = (const float*)d_in[3];
  const float* W     = (const float*)d_in[4];
  const float* bias  = (const float*)d_in[5];
  const float* CW    = (const float*)d_in[6];
  const float* ugW   = (const float*)d_in[7];
  const float* ugb   = (const float*)d_in[8];
  const float* rgW   = (const float*)d_in[9];
  const float* rgb   = (const float*)d_in[10];

  float* h_out = (float*)d_out;

  // ---- workspace carve-up (~78 MB) ----
  char* ws = (char*)d_ws;
  unsigned short* h_bf = (unsigned short*)ws; ws += (size_t)NN * D * 2;        // 25.6 MB
  unsigned short* m_bf = (unsigned short*)ws; ws += (size_t)NN * D * 2;        // 25.6 MB
  unsigned int* packZR = (unsigned int*)ws;   ws += 16 * 8 * 64 * 16;          // 128 KB
  unsigned int* packCW = (unsigned int*)ws;   ws += 8 * 4 * 64 * 16;           // 32 KB
  unsigned int* packW  = (unsigned int*)ws;   ws += 8 * 4 * 64 * 16;           // 32 KB
  int2* arena    = (int2*)ws;                 ws += (size_t)EE * sizeof(int2); // 12.8 MB
  int2* edata    = (int2*)ws;                 ws += (size_t)EE * sizeof(int2); // 12.8 MB
  int* cnt_pb    = (int*)ws;                  ws += SBLK * NB * sizeof(int);   // 306 KB
  int* base_pb   = (int*)ws;                  ws += SBLK * NB * sizeof(int);   // 306 KB
  int* bucket_off= (int*)ws;                  ws += (NB + 1) * sizeof(int);
  int* row_start = (int*)ws;                  ws += (NN + 1) * sizeof(int);

  // ---- CSR build (bucket multisplit) ----
  b_count<<<SBLK, 1024, 0, stream>>>(erow, cnt_pb);
  b_scan<<<1, 1024, 0, stream>>>(cnt_pb, base_pb, bucket_off);
  b_scatter<<<SBLK, 1024, 0, stream>>>(erow, ecol, ew, base_pb, arena);
  b_sort<<<NB, 256, 0, stream>>>(bucket_off, arena, edata, row_start);

  // ---- weight packing + init ----
  k_pack_zr<<<128, 64, 0, stream>>>(ugW, rgW, packZR);
  k_pack_kn<<<32, 64, 0, stream>>>(CW, packCW);
  k_pack_kn<<<32, 64, 0, stream>>>(W, packW);
  init_mfma<<<NN / 32, 256, 0, stream>>>(input, (const short*)packW, bias, h_bf);

  for (int step = 0; step < 3; ++step) {
    spmm_gather_bf<<<(NN + 3) / 4, 256, 0, stream>>>(row_start, edata,
                                                     (const uint4*)h_bf, (uint4*)m_bf);
    gate_mfma<<<NN / 32, 256, 0, stream>>>(h_bf, m_bf, (const short*)packZR, (const short*)packCW,
                                           ugb, rgb, h_bf, h_out, step == 2 ? 1 : 0);
  }
}